// Round 8
// baseline (199.187 us; speedup 1.0000x reference)
//
#include <hip/hip_runtime.h>

// B=4, S=2048, D=1024. out = softmax((x@Wk)(x@Wq)^T / 32) @ (x@Wv), fp32 out.
// GEMMs: 128x256 block tiles, 4 waves (2x2), wave tile 64x128 (0.375 ds_read
// per MFMA -> LDS pipe no longer oversubscribed), BK=32, dbuf 48KB LDS ->
// 2 blocks/CU. 2-deep counted-vmcnt pipeline, 0-conflict XOR-swizzled LDS,
// XCD swizzle, setprio. Softmax fused: scores writes exp(s/32) bf16;
// pv row-sums from A-frags, scales 1/l.

typedef __attribute__((ext_vector_type(8))) short bf16x8;
typedef __attribute__((ext_vector_type(4))) float f32x4;

__device__ __forceinline__ unsigned short f2bf(float f) {
    unsigned int u = __float_as_uint(f);
    u += 0x7fff + ((u >> 16) & 1);   // RNE
    return (unsigned short)(u >> 16);
}
__device__ __forceinline__ float bf2f(unsigned short s) {
    return __uint_as_float((unsigned int)s << 16);
}

__device__ __forceinline__ void gld_lds16(const unsigned short* g, unsigned short* l) {
    __builtin_amdgcn_global_load_lds(
        (const __attribute__((address_space(1))) void*)g,
        (__attribute__((address_space(3))) void*)l, 16, 0, 0);
}

template<int N> __device__ __forceinline__ void vmcnt_wait() {
    if constexpr (N == 0) asm volatile("s_waitcnt vmcnt(0)" ::: "memory");
    else if constexpr (N == 6) asm volatile("s_waitcnt vmcnt(6)" ::: "memory");
}
__device__ __forceinline__ void bar() {
    asm volatile("" ::: "memory");
    __builtin_amdgcn_s_barrier();
    asm volatile("" ::: "memory");
}

// ------------- 128x256x(32*KT) bf16 B^T GEMM, 4 waves (2x2), wave tile 64x128 -------------
// C[m,n] = sum_k A[bm+m,k]*B[bn+n,k]. acc[4 mf][8 nf] 16x16 frags per wave.
// LDS: A 2buf x [128 r][32 bf16] (16KB), B 2buf x [256 r][32 bf16] (32KB).
// phys 16B-unit of row r = u ^ ((r>>1)&3)  (2-way = free; 0 conflicts, r6/r7).
// Stage: inverse-swizzled global src, linear gld_lds dest; 6 loads/thread/tile.
// 2-deep counted-vmcnt(6) pipeline, 2 barriers per K-tile.
template<int KT, bool RS>
__device__ __forceinline__ void gemm_wide(
    const unsigned short* __restrict__ A, const unsigned short* __restrict__ B,
    int lda, int ldb, int bm, int bn,
    unsigned short* As, unsigned short* Bs,
    f32x4 (&acc)[4][8], float (&rs)[4])
{
    const int tid  = threadIdx.x;          // 256 threads
    const int lane = tid & 63;
    const int wave = tid >> 6;             // 0..3
    const int wr = wave >> 1, wc = wave & 1;
    const int lr = lane & 15, kg = lane >> 4;

    // stage map: instr i covers rows i*64 + (t>>2); phys unit t&3;
    // global source unit = (t&3) ^ ((t>>3)&3)  (inverse of read swizzle;
    // row offsets of 64 preserve (row>>1)&3)
    const int srow = tid >> 2;                       // 0..63
    const int ssrc = ((tid & 3) ^ ((tid >> 3) & 3)) * 8;
    const unsigned short* pa0 = A + (size_t)(bm + srow) * lda + ssrc;
    const unsigned short* pa1 = A + (size_t)(bm + 64 + srow) * lda + ssrc;
    const unsigned short* pb0 = B + (size_t)(bn + srow) * ldb + ssrc;
    const unsigned short* pb1 = B + (size_t)(bn + 64 + srow) * ldb + ssrc;
    const unsigned short* pb2 = B + (size_t)(bn + 128 + srow) * ldb + ssrc;
    const unsigned short* pb3 = B + (size_t)(bn + 192 + srow) * ldb + ssrc;

    // read-side: phys unit = kg ^ ((lr>>1)&3)
    const int phys = (kg ^ ((lr >> 1) & 3)) * 8;
    const int aoff = (wr * 64 + lr) * 32 + phys;     // + mf*512, buf +4096
    const int boff = (wc * 128 + lr) * 32 + phys;    // + nf*512, buf +8192

    auto stage = [&](int buf, int kt) {
        unsigned short* da = As + buf * 4096 + wave * 512;   // wave-uniform dests
        unsigned short* db = Bs + buf * 8192 + wave * 512;
        const int go = kt * 32;
        gld_lds16(pa0 + go, da);
        gld_lds16(pa1 + go, da + 2048);
        gld_lds16(pb0 + go, db);
        gld_lds16(pb1 + go, db + 2048);
        gld_lds16(pb2 + go, db + 4096);
        gld_lds16(pb3 + go, db + 6144);
    };

    // prologue: tiles 0,1 in flight (12 loads); wait tile 0 only (6 remain)
    stage(0, 0);
    stage(1, 1);
    vmcnt_wait<6>();
    bar();

    for (int kt = 0; kt < KT; ++kt) {
        const int c = kt & 1;
        const unsigned short* Ab = As + c * 4096 + aoff;
        const unsigned short* Bb = Bs + c * 8192 + boff;

        bf16x8 af[4], bfr[8];
        #pragma unroll
        for (int mf = 0; mf < 4; mf++)
            af[mf] = *reinterpret_cast<const bf16x8*>(Ab + mf * 512);
        #pragma unroll
        for (int nf = 0; nf < 8; nf++)
            bfr[nf] = *reinterpret_cast<const bf16x8*>(Bb + nf * 512);
        __builtin_amdgcn_s_setprio(1);
        #pragma unroll
        for (int mf = 0; mf < 4; mf++)
            #pragma unroll
            for (int nf = 0; nf < 8; nf++)
                acc[mf][nf] = __builtin_amdgcn_mfma_f32_16x16x32_bf16(af[mf], bfr[nf], acc[mf][nf], 0, 0, 0);
        __builtin_amdgcn_s_setprio(0);
        if constexpr (RS) {
            #pragma unroll
            for (int mf = 0; mf < 4; mf++)
                #pragma unroll
                for (int e = 0; e < 8; e++) rs[mf] += bf2f(((unsigned short*)&af[mf])[e]);
        }

        if (kt == KT - 1) break;
        bar();                     // all waves done reading buf c
        if (kt + 2 < KT) {
            stage(c, kt + 2);      // overwrite buf c with tile kt+2
            vmcnt_wait<6>();       // tile kt+1 (issued a full tile ago) landed
        } else {
            vmcnt_wait<0>();
        }
        bar();                     // buf (kt+1)&1 globally ready
    }
}

// ---------------- x f32 -> bf16 ----------------
__global__ __launch_bounds__(256) void convert_x(
    const float* __restrict__ x, unsigned short* __restrict__ xb)
{
    const size_t idx = (size_t)blockIdx.x * 256 + threadIdx.x;
    const float4* xi = reinterpret_cast<const float4*>(x) + idx * 2;
    float4 v0 = xi[0], v1 = xi[1];
    ushort4 a = { f2bf(v0.x), f2bf(v0.y), f2bf(v0.z), f2bf(v0.w) };
    ushort4 b = { f2bf(v1.x), f2bf(v1.y), f2bf(v1.z), f2bf(v1.w) };
    ushort4* xo = reinterpret_cast<ushort4*>(xb) + idx * 2;
    xo[0] = a; xo[1] = b;
}

// ---------------- W [K][N] f32 -> wT [N][K] bf16 ----------------
__global__ __launch_bounds__(256) void transpose_w(
    const float* __restrict__ w0, const float* __restrict__ w1, const float* __restrict__ w2,
    unsigned short* __restrict__ wT)
{
    __shared__ unsigned short T[64][72];
    const int z = blockIdx.z;
    const float* w = (z == 0) ? w0 : (z == 1 ? w1 : w2);
    unsigned short* o = wT + (size_t)z * 1024 * 1024;
    const int k0 = blockIdx.y * 64, n0 = blockIdx.x * 64;
    const int tid = threadIdx.x;
    const int r = tid >> 4, c4 = (tid & 15) * 4;
    #pragma unroll
    for (int i = 0; i < 4; i++) {
        int kr = r + i * 16;
        float4 v = *reinterpret_cast<const float4*>(&w[(size_t)(k0 + kr) * 1024 + n0 + c4]);
        T[c4 + 0][kr] = f2bf(v.x);
        T[c4 + 1][kr] = f2bf(v.y);
        T[c4 + 2][kr] = f2bf(v.z);
        T[c4 + 3][kr] = f2bf(v.w);
    }
    __syncthreads();
    #pragma unroll
    for (int i = 0; i < 4; i++) {
        int n = r + i * 16;
        ushort4 v = *reinterpret_cast<const ushort4*>(&T[n][c4]);
        *reinterpret_cast<ushort4*>(&o[(size_t)(n0 + n) * 1024 + k0 + c4]) = v;
    }
}

// ---------------- projections: 128x256 tiles, grid 768 ----------------
__global__ __launch_bounds__(256, 2) void proj_gemm(
    const unsigned short* __restrict__ xb, const unsigned short* __restrict__ wT,
    unsigned short* __restrict__ vk, unsigned short* __restrict__ vq,
    unsigned short* __restrict__ vvT)
{
    __shared__ unsigned short As[2 * 128 * 32], Bs[2 * 256 * 32];   // 48 KB
    const int bid = blockIdx.x;
    const int wg  = (bid & 7) * 96 + (bid >> 3);   // 768 % 8 == 0, bijective
    const int z   = wg >> 8;
    const int rem = wg & 255;
    const int bm  = (rem >> 2) * 128;
    const int bn  = (rem & 3) * 256;
    const unsigned short* Bw = wT + (size_t)z * 1024 * 1024;

    f32x4 acc[4][8] = {};
    float rs[4] = {};
    gemm_wide<32, false>(xb, Bw, 1024, 1024, bm, bn, As, Bs, acc, rs);

    const int tid = threadIdx.x, lane = tid & 63, wave = tid >> 6;
    const int wr = wave >> 1, wc = wave & 1, lr = lane & 15, kg = lane >> 4;
    if (z < 2) {
        unsigned short* out = z ? vq : vk;
        #pragma unroll
        for (int mf = 0; mf < 4; mf++)
            #pragma unroll
            for (int nf = 0; nf < 8; nf++)
                #pragma unroll
                for (int r = 0; r < 4; r++)
                    out[(size_t)(bm + wr * 64 + mf * 16 + kg * 4 + r) * 1024
                        + bn + wc * 128 + nf * 16 + lr] = f2bf(acc[mf][nf][r]);
    } else {
        const int batch = bm >> 11;                 // 128-tiles never span batches
        unsigned short* o = vvT + (size_t)batch * 1024 * 2048;
        #pragma unroll
        for (int mf = 0; mf < 4; mf++)
            #pragma unroll
            for (int nf = 0; nf < 8; nf++) {
                ushort4 v = { f2bf(acc[mf][nf][0]), f2bf(acc[mf][nf][1]),
                              f2bf(acc[mf][nf][2]), f2bf(acc[mf][nf][3]) };
                *reinterpret_cast<ushort4*>(
                    &o[(size_t)(bn + wc * 128 + nf * 16 + lr) * 2048
                       + (bm & 2047) + wr * 64 + mf * 16 + kg * 4]) = v;
            }
    }
}

// ---------------- scores: 128x256 tiles, grid 512; epilogue writes exp(s/32) bf16 ----------------
__global__ __launch_bounds__(256, 2) void scores_gemm(
    const unsigned short* __restrict__ vk, const unsigned short* __restrict__ vq,
    unsigned short* __restrict__ P)
{
    __shared__ unsigned short As[2 * 128 * 32], Bs[2 * 256 * 32];   // 48 KB
    const int bid = blockIdx.x;
    const int wg  = (bid & 7) * 64 + (bid >> 3);    // 512 % 8 == 0
    const int z   = wg >> 7;
    const int rem = wg & 127;
    const int bm  = (rem >> 3) * 128;
    const int bn  = (rem & 7) * 256;
    const unsigned short* A = vk + (size_t)z * 2048 * 1024;
    const unsigned short* B = vq + (size_t)z * 2048 * 1024;
    unsigned short* out = P + (size_t)z * 2048 * 2048;

    f32x4 acc[4][8] = {};
    float rs[4] = {};
    gemm_wide<32, false>(A, B, 1024, 1024, bm, bn, As, Bs, acc, rs);

    const int tid = threadIdx.x, lane = tid & 63, wave = tid >> 6;
    const int wr = wave >> 1, wc = wave & 1, lr = lane & 15, kg = lane >> 4;
    #pragma unroll
    for (int mf = 0; mf < 4; mf++)
        #pragma unroll
        for (int nf = 0; nf < 8; nf++)
            #pragma unroll
            for (int r = 0; r < 4; r++)
                out[(size_t)(bm + wr * 64 + mf * 16 + kg * 4 + r) * 2048
                    + bn + wc * 128 + nf * 16 + lr]
                    = f2bf(__expf(acc[mf][nf][r] * 0.03125f));
}

// ---------------- PV: 128x256 tiles, K=2048, grid 256; row-sums; out = acc/l ----------------
__global__ __launch_bounds__(256, 2) void pv_gemm(
    const unsigned short* __restrict__ P, const unsigned short* __restrict__ vvT,
    float* __restrict__ out)
{
    __shared__ unsigned short As[2 * 128 * 32], Bs[2 * 256 * 32];   // 48 KB
    const int bid = blockIdx.x;
    const int wg  = (bid & 7) * 32 + (bid >> 3);    // 256 % 8 == 0
    const int z   = wg >> 6;
    const int rem = wg & 63;
    const int bm  = (rem >> 2) * 128;
    const int bn  = (rem & 3) * 256;
    const unsigned short* A = P   + (size_t)z * 2048 * 2048;
    const unsigned short* B = vvT + (size_t)z * 1024 * 2048;
    float* o = out + (size_t)z * 2048 * 1024;

    f32x4 acc[4][8] = {};
    float rs[4] = {};
    gemm_wide<64, true>(A, B, 2048, 2048, bm, bn, As, Bs, acc, rs);

    const int tid = threadIdx.x, lane = tid & 63, wave = tid >> 6;
    const int wr = wave >> 1, wc = wave & 1, lr = lane & 15, kg = lane >> 4;

    // rs[mf] at lane (lr,kg): partial row-sum of row wr*64+mf*16+lr over kg's octets.
    #pragma unroll
    for (int mf = 0; mf < 4; mf++) {
        rs[mf] += __shfl_xor(rs[mf], 16);
        rs[mf] += __shfl_xor(rs[mf], 32);
    }
    #pragma unroll
    for (int mf = 0; mf < 4; mf++)
        #pragma unroll
        for (int r = 0; r < 4; r++) {
            const float l = __shfl(rs[mf], kg * 4 + r);   // row-sum for this output row
            const float inv = 1.0f / l;
            #pragma unroll
            for (int nf = 0; nf < 8; nf++)
                o[(size_t)(bm + wr * 64 + mf * 16 + kg * 4 + r) * 1024
                  + bn + wc * 128 + nf * 16 + lr] = acc[mf][nf][r] * inv;
        }
}

extern "C" void kernel_launch(void* const* d_in, const int* in_sizes, int n_in,
                              void* d_out, int out_size, void* d_ws, size_t ws_size,
                              hipStream_t stream) {
    const float* x  = (const float*)d_in[0];
    const float* wk = (const float*)d_in[1];
    const float* wq = (const float*)d_in[2];
    const float* wv = (const float*)d_in[3];
    float* out = (float*)d_out;

    char* ws = (char*)d_ws;
    const size_t MB = 1024 * 1024;
    unsigned short* xb  = (unsigned short*)(ws);             // 16MB, dead after proj
    unsigned short* wT  = (unsigned short*)(ws + 16 * MB);   // 6MB, dead after proj
    unsigned short* P   = (unsigned short*)(ws);             // 32MB bf16 exp(s), aliases xb/wT
    unsigned short* vk  = (unsigned short*)(ws + 64 * MB);
    unsigned short* vq  = (unsigned short*)(ws + 80 * MB);
    unsigned short* vvT = (unsigned short*)(ws + 96 * MB);

    convert_x  <<<dim3(4096),      256, 0, stream>>>(x, xb);
    transpose_w<<<dim3(16, 16, 3), 256, 0, stream>>>(wk, wq, wv, wT);
    proj_gemm  <<<dim3(768),       256, 0, stream>>>(xb, wT, vk, vq, vvT);
    scores_gemm<<<dim3(512),       256, 0, stream>>>(vk, vq, P);
    pv_gemm    <<<dim3(256),       256, 0, stream>>>(P, vvT, out);
}

// Round 9
// 172.022 us; speedup vs baseline: 1.1579x; 1.1579x over previous
//
#include <hip/hip_runtime.h>

// B=4, S=2048, D=1024. out = softmax((x@Wk)(x@Wq)^T / 32) @ (x@Wv), fp32 out.
// Algebraic restructure: G = Wk Wq^T precomputed (Gt[j,a] = Wq[j,:]·Wk[a,:]),
// y = x·G replaces BOTH vk and vq projections; scores = y·x^T.
// GEMM core identical to round-6 best: 128x128 tiles, 4 waves (2x2), BK=64,
// dbuf 64KB LDS -> 2 blocks/CU, 2-deep counted-vmcnt pipeline, 0-conflict
// XOR-swizzled LDS, XCD swizzle, setprio. Softmax fused: scores writes
// exp(s/32) bf16 P; pv row-sums from A-frags, scales 1/l.

typedef __attribute__((ext_vector_type(8))) short bf16x8;
typedef __attribute__((ext_vector_type(4))) float f32x4;

__device__ __forceinline__ unsigned short f2bf(float f) {
    unsigned int u = __float_as_uint(f);
    u += 0x7fff + ((u >> 16) & 1);   // RNE
    return (unsigned short)(u >> 16);
}
__device__ __forceinline__ float bf2f(unsigned short s) {
    return __uint_as_float((unsigned int)s << 16);
}

__device__ __forceinline__ void gld_lds16(const unsigned short* g, unsigned short* l) {
    __builtin_amdgcn_global_load_lds(
        (const __attribute__((address_space(1))) void*)g,
        (__attribute__((address_space(3))) void*)l, 16, 0, 0);
}

template<int N> __device__ __forceinline__ void vmcnt_wait() {
    if constexpr (N == 0) asm volatile("s_waitcnt vmcnt(0)" ::: "memory");
    else if constexpr (N == 8) asm volatile("s_waitcnt vmcnt(8)" ::: "memory");
}
__device__ __forceinline__ void bar() {
    asm volatile("" ::: "memory");
    __builtin_amdgcn_s_barrier();
    asm volatile("" ::: "memory");
}

// ---------------- 128x128x(64*KT) bf16 B^T GEMM, 4 waves (2x2) ----------------
// C[m,n] = sum_k A[bm+m,k]*B[bn+n,k]. Wave tile 64x64: acc[4][4] 16x16 frags.
// LDS per operand: 2 buf x 2 kh x [128 rows][32 bf16]; phys 16B-unit of row r
// holds global unit u ^ ((r>>1)&3) (0 conflicts, verified r4-r8). Stage:
// inverse-swizzled global src, linear global_load_lds dest. 2-deep
// counted-vmcnt pipeline, 2 barriers per K-tile.  [identical to round-6]
template<int KT, bool RS>
__device__ __forceinline__ void gemm4(
    const unsigned short* __restrict__ A, const unsigned short* __restrict__ B,
    int lda, int ldb, int bm, int bn,
    unsigned short* As, unsigned short* Bs,
    f32x4 (&acc)[4][4], float (&rs)[4])
{
    const int tid  = threadIdx.x;
    const int lane = tid & 63;
    const int wave = tid >> 6;            // 0..3
    const int wr = wave >> 1, wc = wave & 1;
    const int lr = lane & 15, kg = lane >> 4;

    const int srow = tid >> 2;                       // 0..63
    const int ssrc = ((tid & 3) ^ ((tid >> 3) & 3)) * 8;
    const unsigned short* pa0 = A + (size_t)(bm + srow) * lda + ssrc;
    const unsigned short* pa1 = A + (size_t)(bm + 64 + srow) * lda + ssrc;
    const unsigned short* pb0 = B + (size_t)(bn + srow) * ldb + ssrc;
    const unsigned short* pb1 = B + (size_t)(bn + 64 + srow) * ldb + ssrc;

    const int phys = (kg ^ ((lr >> 1) & 3)) * 8;
    const int aoff = (wr * 64 + lr) * 32 + phys;
    const int boff = (wc * 64 + lr) * 32 + phys;

    auto stage = [&](int buf, int kt) {
        unsigned short* da = As + buf * 8192 + wave * 512;
        unsigned short* db = Bs + buf * 8192 + wave * 512;
        #pragma unroll
        for (int kh = 0; kh < 2; kh++) {
            const int go = kt * 64 + kh * 32;
            gld_lds16(pa0 + go, da + kh * 4096);
            gld_lds16(pa1 + go, da + kh * 4096 + 2048);
            gld_lds16(pb0 + go, db + kh * 4096);
            gld_lds16(pb1 + go, db + kh * 4096 + 2048);
        }
    };

    stage(0, 0);
    stage(1, 1);
    vmcnt_wait<8>();
    bar();

    for (int kt = 0; kt < KT; ++kt) {
        const int c = kt & 1;
        const unsigned short* Ab = As + c * 8192 + aoff;
        const unsigned short* Bb = Bs + c * 8192 + boff;

        #pragma unroll
        for (int kh = 0; kh < 2; kh++) {
            bf16x8 af[4], bf[4];
            #pragma unroll
            for (int mf = 0; mf < 4; mf++)
                af[mf] = *reinterpret_cast<const bf16x8*>(Ab + kh * 4096 + mf * 512);
            #pragma unroll
            for (int nf = 0; nf < 4; nf++)
                bf[nf] = *reinterpret_cast<const bf16x8*>(Bb + kh * 4096 + nf * 512);
            __builtin_amdgcn_s_setprio(1);
            #pragma unroll
            for (int mf = 0; mf < 4; mf++)
                #pragma unroll
                for (int nf = 0; nf < 4; nf++)
                    acc[mf][nf] = __builtin_amdgcn_mfma_f32_16x16x32_bf16(af[mf], bf[nf], acc[mf][nf], 0, 0, 0);
            __builtin_amdgcn_s_setprio(0);
            if constexpr (RS) {
                #pragma unroll
                for (int mf = 0; mf < 4; mf++)
                    #pragma unroll
                    for (int e = 0; e < 8; e++) rs[mf] += bf2f(((unsigned short*)&af[mf])[e]);
            }
        }

        if (kt == KT - 1) break;
        bar();                     // all waves done reading buf c
        if (kt + 2 < KT) {
            stage(c, kt + 2);      // overwrite buf c with tile kt+2
            vmcnt_wait<8>();       // tile kt+1 (issued a full tile ago) landed
        } else {
            vmcnt_wait<0>();
        }
        bar();                     // buf (kt+1)&1 globally ready
    }
}

// ---------------- f32 -> bf16 cast (8 elems/thread) ----------------
__global__ __launch_bounds__(256) void convert_bf16(
    const float* __restrict__ src, unsigned short* __restrict__ dst)
{
    const size_t idx = (size_t)blockIdx.x * 256 + threadIdx.x;
    const float4* xi = reinterpret_cast<const float4*>(src) + idx * 2;
    float4 v0 = xi[0], v1 = xi[1];
    ushort4 a = { f2bf(v0.x), f2bf(v0.y), f2bf(v0.z), f2bf(v0.w) };
    ushort4 b = { f2bf(v1.x), f2bf(v1.y), f2bf(v1.z), f2bf(v1.w) };
    ushort4* xo = reinterpret_cast<ushort4*>(dst) + idx * 2;
    xo[0] = a; xo[1] = b;
}

// ---------------- Wv [K][N] f32 -> wvT [N][K] bf16 ----------------
__global__ __launch_bounds__(256) void transpose_w1(
    const float* __restrict__ w, unsigned short* __restrict__ o)
{
    __shared__ unsigned short T[64][72];
    const int k0 = blockIdx.y * 64, n0 = blockIdx.x * 64;
    const int tid = threadIdx.x;
    const int r = tid >> 4, c4 = (tid & 15) * 4;
    #pragma unroll
    for (int i = 0; i < 4; i++) {
        int kr = r + i * 16;
        float4 v = *reinterpret_cast<const float4*>(&w[(size_t)(k0 + kr) * 1024 + n0 + c4]);
        T[c4 + 0][kr] = f2bf(v.x);
        T[c4 + 1][kr] = f2bf(v.y);
        T[c4 + 2][kr] = f2bf(v.z);
        T[c4 + 3][kr] = f2bf(v.w);
    }
    __syncthreads();
    #pragma unroll
    for (int i = 0; i < 4; i++) {
        int n = r + i * 16;
        ushort4 v = *reinterpret_cast<const ushort4*>(&T[n][c4]);
        *reinterpret_cast<ushort4*>(&o[(size_t)(n0 + n) * 1024 + k0 + c4]) = v;
    }
}

// ---------------- Gt[j,a] = Wq[j,:]·Wk[a,:]  (1024x1024x1024, grid 64) ----------------
__global__ __launch_bounds__(256, 2) void g_gemm(
    const unsigned short* __restrict__ wqb, const unsigned short* __restrict__ wkb,
    unsigned short* __restrict__ Gt)
{
    __shared__ unsigned short As[2 * 128 * 64], Bs[2 * 128 * 64];   // 64 KB
    const int bid = blockIdx.x;
    const int wg  = (bid & 7) * 8 + (bid >> 3);     // 64 % 8 == 0, bijective
    const int bm  = (wg >> 3) * 128;
    const int bn  = (wg & 7) * 128;

    f32x4 acc[4][4] = {};
    float rs[4] = {};
    gemm4<16, false>(wqb, wkb, 1024, 1024, bm, bn, As, Bs, acc, rs);

    const int tid = threadIdx.x, lane = tid & 63, wave = tid >> 6;
    const int wr = wave >> 1, wc = wave & 1, lr = lane & 15, kg = lane >> 4;
    #pragma unroll
    for (int mf = 0; mf < 4; mf++)
        #pragma unroll
        for (int nf = 0; nf < 4; nf++)
            #pragma unroll
            for (int r = 0; r < 4; r++)
                Gt[(size_t)(bm + wr * 64 + mf * 16 + kg * 4 + r) * 1024
                   + bn + wc * 64 + nf * 16 + lr] = f2bf(acc[mf][nf][r]);
}

// ---------------- projections: z=0: y = x·G; z=1: vvT (transposed). grid 1024 ----------------
__global__ __launch_bounds__(256, 2) void proj_gemm(
    const unsigned short* __restrict__ xb, const unsigned short* __restrict__ Gt,
    const unsigned short* __restrict__ wvT,
    unsigned short* __restrict__ y, unsigned short* __restrict__ vvT)
{
    __shared__ unsigned short As[2 * 128 * 64], Bs[2 * 128 * 64];   // 64 KB
    const int bid = blockIdx.x;
    const int wg  = (bid & 7) * 128 + (bid >> 3);   // 1024 % 8 == 0, bijective
    const int z   = wg >> 9;
    const int rem = wg & 511;
    const int bm  = (rem >> 3) * 128;
    const int bn  = (rem & 7) * 128;
    const unsigned short* Bw = z ? wvT : Gt;

    f32x4 acc[4][4] = {};
    float rs[4] = {};
    gemm4<16, false>(xb, Bw, 1024, 1024, bm, bn, As, Bs, acc, rs);

    const int tid = threadIdx.x, lane = tid & 63, wave = tid >> 6;
    const int wr = wave >> 1, wc = wave & 1, lr = lane & 15, kg = lane >> 4;
    if (z == 0) {
        #pragma unroll
        for (int mf = 0; mf < 4; mf++)
            #pragma unroll
            for (int nf = 0; nf < 4; nf++)
                #pragma unroll
                for (int r = 0; r < 4; r++)
                    y[(size_t)(bm + wr * 64 + mf * 16 + kg * 4 + r) * 1024
                      + bn + wc * 64 + nf * 16 + lr] = f2bf(acc[mf][nf][r]);
    } else {
        const int batch = bm >> 11;                 // 128-tiles never span batches
        unsigned short* o = vvT + (size_t)batch * 1024 * 2048;
        #pragma unroll
        for (int mf = 0; mf < 4; mf++)
            #pragma unroll
            for (int nf = 0; nf < 4; nf++) {
                ushort4 v = { f2bf(acc[mf][nf][0]), f2bf(acc[mf][nf][1]),
                              f2bf(acc[mf][nf][2]), f2bf(acc[mf][nf][3]) };
                *reinterpret_cast<ushort4*>(
                    &o[(size_t)(bn + wc * 64 + nf * 16 + lr) * 2048
                       + (bm & 2047) + wr * 64 + mf * 16 + kg * 4]) = v;
            }
    }
}

// ---------------- scores: y[b]·xb[b]^T / 32, exp epilogue -> bf16 P. grid 1024 ----------------
__global__ __launch_bounds__(256, 2) void scores_gemm(
    const unsigned short* __restrict__ y, const unsigned short* __restrict__ xb,
    unsigned short* __restrict__ P)
{
    __shared__ unsigned short As[2 * 128 * 64], Bs[2 * 128 * 64];   // 64 KB
    const int bid = blockIdx.x;
    const int wg  = (bid & 7) * 128 + (bid >> 3);   // 1024 % 8 == 0
    const int z   = wg >> 8;
    const int rem = wg & 255;
    const int bm  = (rem >> 4) * 128;
    const int bn  = (rem & 15) * 128;
    const unsigned short* A = y  + (size_t)z * 2048 * 1024;
    const unsigned short* B = xb + (size_t)z * 2048 * 1024;
    unsigned short* out = P + (size_t)z * 2048 * 2048;

    f32x4 acc[4][4] = {};
    float rs[4] = {};
    gemm4<16, false>(A, B, 1024, 1024, bm, bn, As, Bs, acc, rs);

    const int tid = threadIdx.x, lane = tid & 63, wave = tid >> 6;
    const int wr = wave >> 1, wc = wave & 1, lr = lane & 15, kg = lane >> 4;
    #pragma unroll
    for (int mf = 0; mf < 4; mf++)
        #pragma unroll
        for (int nf = 0; nf < 4; nf++)
            #pragma unroll
            for (int r = 0; r < 4; r++)
                out[(size_t)(bm + wr * 64 + mf * 16 + kg * 4 + r) * 2048
                    + bn + wc * 64 + nf * 16 + lr]
                    = f2bf(__expf(acc[mf][nf][r] * 0.03125f));
}

// ---------------- PV: 128x128 tiles, K=2048, grid 512; row-sums; out = acc/l ----------------
__global__ __launch_bounds__(256, 2) void pv_gemm(
    const unsigned short* __restrict__ P, const unsigned short* __restrict__ vvT,
    float* __restrict__ out)
{
    __shared__ unsigned short As[2 * 128 * 64], Bs[2 * 128 * 64];   // 64 KB
    const int bid = blockIdx.x;
    const int wg  = (bid & 7) * 64 + (bid >> 3);    // 512 % 8 == 0
    const int z   = wg >> 7;
    const int rem = wg & 127;
    const int bm  = (rem >> 3) * 128;
    const int bn  = (rem & 7) * 128;
    const unsigned short* A = P   + (size_t)z * 2048 * 2048;
    const unsigned short* B = vvT + (size_t)z * 1024 * 2048;
    float* o = out + (size_t)z * 2048 * 1024;

    f32x4 acc[4][4] = {};
    float rs[4] = {};
    gemm4<32, true>(A, B, 2048, 2048, bm, bn, As, Bs, acc, rs);

    const int tid = threadIdx.x, lane = tid & 63, wave = tid >> 6;
    const int wr = wave >> 1, wc = wave & 1, lr = lane & 15, kg = lane >> 4;

    #pragma unroll
    for (int mf = 0; mf < 4; mf++) {
        rs[mf] += __shfl_xor(rs[mf], 16);
        rs[mf] += __shfl_xor(rs[mf], 32);
    }
    #pragma unroll
    for (int mf = 0; mf < 4; mf++)
        #pragma unroll
        for (int r = 0; r < 4; r++) {
            const float l = __shfl(rs[mf], kg * 4 + r);   // row-sum for this output row
            const float inv = 1.0f / l;
            #pragma unroll
            for (int nf = 0; nf < 4; nf++)
                o[(size_t)(bm + wr * 64 + mf * 16 + kg * 4 + r) * 1024
                  + bn + wc * 64 + nf * 16 + lr] = acc[mf][nf][r] * inv;
        }
}

extern "C" void kernel_launch(void* const* d_in, const int* in_sizes, int n_in,
                              void* d_out, int out_size, void* d_ws, size_t ws_size,
                              hipStream_t stream) {
    const float* x  = (const float*)d_in[0];
    const float* wk = (const float*)d_in[1];
    const float* wq = (const float*)d_in[2];
    const float* wv = (const float*)d_in[3];
    float* out = (float*)d_out;

    char* ws = (char*)d_ws;
    const size_t MB = 1024 * 1024;
    unsigned short* xb  = (unsigned short*)(ws);             // 16MB  x bf16
    unsigned short* y   = (unsigned short*)(ws + 16 * MB);   // 16MB  x·G bf16
    unsigned short* wqb = (unsigned short*)(ws + 32 * MB);   // 2MB
    unsigned short* wkb = (unsigned short*)(ws + 34 * MB);   // 2MB
    unsigned short* Gt  = (unsigned short*)(ws + 36 * MB);   // 2MB  Gt[j,a]
    unsigned short* wvT = (unsigned short*)(ws + 38 * MB);   // 2MB
    unsigned short* vvT = (unsigned short*)(ws + 40 * MB);   // 16MB
    unsigned short* P   = (unsigned short*)(ws + 56 * MB);   // 32MB bf16 exp(s)

    convert_bf16<<<dim3(4096),     256, 0, stream>>>(x,  xb);
    convert_bf16<<<dim3(512),      256, 0, stream>>>(wq, wqb);
    convert_bf16<<<dim3(512),      256, 0, stream>>>(wk, wkb);
    transpose_w1<<<dim3(16, 16),   256, 0, stream>>>(wv, wvT);
    g_gemm      <<<dim3(64),       256, 0, stream>>>(wqb, wkb, Gt);
    proj_gemm   <<<dim3(1024),     256, 0, stream>>>(xb, Gt, wvT, y, vvT);
    scores_gemm <<<dim3(1024),     256, 0, stream>>>(y, xb, P);
    pv_gemm     <<<dim3(512),      256, 0, stream>>>(P, vvT, out);
}

// Round 10
// 169.279 us; speedup vs baseline: 1.1767x; 1.0162x over previous
//
#include <hip/hip_runtime.h>

// B=4, S=2048, D=1024. out = softmax((x@Wk)(x@Wq)^T / 32) @ (x@Wv), fp32 out.
// Algebra: Gt[e,d] = Wq[e,:]·Wk[d,:]; y = x·G (via B^T gemm vs Gt); scores = y·x^T.
// GEMM core identical to round-6/9: 128x128 tiles, 4 waves (2x2), BK=64,
// dbuf 64KB LDS (2 blocks/CU), 2-deep counted-vmcnt pipeline, 0-conflict
// XOR-swizzled LDS, XCD swizzle, setprio. Softmax fused: scores writes
// exp(s/32) bf16 P; pv row-sums via ones-MFMA (exact, shuffle-free).
// Stage 1 (convert_x | transpose_wv | g_gemm) merged into ONE launch.

typedef __attribute__((ext_vector_type(8))) short bf16x8;
typedef __attribute__((ext_vector_type(4))) float f32x4;

__device__ __forceinline__ unsigned short f2bf(float f) {
    unsigned int u = __float_as_uint(f);
    u += 0x7fff + ((u >> 16) & 1);   // RNE
    return (unsigned short)(u >> 16);
}

__device__ __forceinline__ void gld_lds16(const unsigned short* g, unsigned short* l) {
    __builtin_amdgcn_global_load_lds(
        (const __attribute__((address_space(1))) void*)g,
        (__attribute__((address_space(3))) void*)l, 16, 0, 0);
}

template<int N> __device__ __forceinline__ void vmcnt_wait() {
    if constexpr (N == 0) asm volatile("s_waitcnt vmcnt(0)" ::: "memory");
    else if constexpr (N == 8) asm volatile("s_waitcnt vmcnt(8)" ::: "memory");
}
__device__ __forceinline__ void bar() {
    asm volatile("" ::: "memory");
    __builtin_amdgcn_s_barrier();
    asm volatile("" ::: "memory");
}

// ---------------- 128x128x(64*KT) bf16 B^T GEMM, 4 waves (2x2) ----------------
// [core identical to round-6/9; RS now = ones-MFMA row-sum into os]
template<int KT, bool RS>
__device__ __forceinline__ void gemm4(
    const unsigned short* __restrict__ A, const unsigned short* __restrict__ B,
    int lda, int ldb, int bm, int bn,
    unsigned short* As, unsigned short* Bs,
    f32x4 (&acc)[4][4], f32x4 (&os)[4])
{
    const int tid  = threadIdx.x;
    const int lane = tid & 63;
    const int wave = tid >> 6;            // 0..3
    const int wr = wave >> 1, wc = wave & 1;
    const int lr = lane & 15, kg = lane >> 4;

    const bf16x8 ONES = { (short)0x3F80, (short)0x3F80, (short)0x3F80, (short)0x3F80,
                          (short)0x3F80, (short)0x3F80, (short)0x3F80, (short)0x3F80 };

    const int srow = tid >> 2;                       // 0..63
    const int ssrc = ((tid & 3) ^ ((tid >> 3) & 3)) * 8;
    const unsigned short* pa0 = A + (size_t)(bm + srow) * lda + ssrc;
    const unsigned short* pa1 = A + (size_t)(bm + 64 + srow) * lda + ssrc;
    const unsigned short* pb0 = B + (size_t)(bn + srow) * ldb + ssrc;
    const unsigned short* pb1 = B + (size_t)(bn + 64 + srow) * ldb + ssrc;

    const int phys = (kg ^ ((lr >> 1) & 3)) * 8;
    const int aoff = (wr * 64 + lr) * 32 + phys;
    const int boff = (wc * 64 + lr) * 32 + phys;

    auto stage = [&](int buf, int kt) {
        unsigned short* da = As + buf * 8192 + wave * 512;
        unsigned short* db = Bs + buf * 8192 + wave * 512;
        #pragma unroll
        for (int kh = 0; kh < 2; kh++) {
            const int go = kt * 64 + kh * 32;
            gld_lds16(pa0 + go, da + kh * 4096);
            gld_lds16(pa1 + go, da + kh * 4096 + 2048);
            gld_lds16(pb0 + go, db + kh * 4096);
            gld_lds16(pb1 + go, db + kh * 4096 + 2048);
        }
    };

    stage(0, 0);
    stage(1, 1);
    vmcnt_wait<8>();
    bar();

    for (int kt = 0; kt < KT; ++kt) {
        const int c = kt & 1;
        const unsigned short* Ab = As + c * 8192 + aoff;
        const unsigned short* Bb = Bs + c * 8192 + boff;

        #pragma unroll
        for (int kh = 0; kh < 2; kh++) {
            bf16x8 af[4], bf[4];
            #pragma unroll
            for (int mf = 0; mf < 4; mf++)
                af[mf] = *reinterpret_cast<const bf16x8*>(Ab + kh * 4096 + mf * 512);
            #pragma unroll
            for (int nf = 0; nf < 4; nf++)
                bf[nf] = *reinterpret_cast<const bf16x8*>(Bb + kh * 4096 + nf * 512);
            __builtin_amdgcn_s_setprio(1);
            #pragma unroll
            for (int mf = 0; mf < 4; mf++)
                #pragma unroll
                for (int nf = 0; nf < 4; nf++)
                    acc[mf][nf] = __builtin_amdgcn_mfma_f32_16x16x32_bf16(af[mf], bf[nf], acc[mf][nf], 0, 0, 0);
            if constexpr (RS) {
                // row-sum: D[row,col] = sum_k af[row,k]*1 (exact, lane-replicated)
                #pragma unroll
                for (int mf = 0; mf < 4; mf++)
                    os[mf] = __builtin_amdgcn_mfma_f32_16x16x32_bf16(af[mf], ONES, os[mf], 0, 0, 0);
            }
            __builtin_amdgcn_s_setprio(0);
        }

        if (kt == KT - 1) break;
        bar();                     // all waves done reading buf c
        if (kt + 2 < KT) {
            stage(c, kt + 2);      // overwrite buf c with tile kt+2
            vmcnt_wait<8>();       // tile kt+1 (issued a full tile ago) landed
        } else {
            vmcnt_wait<0>();
        }
        bar();                     // buf (kt+1)&1 globally ready
    }
}

// ================ stage 1 (merged): convert_x | transpose_wv | g_gemm ================
// blocks [0,4096): x f32 -> xb bf16
// blocks [4096,4352): Wv [k][n] f32 -> wvT [n][k] bf16
// blocks [4352,4608): Gt[m,n] = sum_j Wq[m,j]*Wk[n,j]  (64x64 tiles, f32 in, bf16 out)
__global__ __launch_bounds__(256) void stage1(
    const float* __restrict__ x,  unsigned short* __restrict__ xb,
    const float* __restrict__ wv, unsigned short* __restrict__ wvT,
    const float* __restrict__ wq, const float* __restrict__ wk,
    unsigned short* __restrict__ Gt)
{
    __shared__ unsigned short SM[4608];
    const int bid = blockIdx.x;
    const int tid = threadIdx.x;

    if (bid < 4096) {
        // ---- convert x -> bf16, 8 elems/thread ----
        const size_t idx = (size_t)bid * 256 + tid;
        const float4* xi = reinterpret_cast<const float4*>(x) + idx * 2;
        float4 v0 = xi[0], v1 = xi[1];
        ushort4 a = { f2bf(v0.x), f2bf(v0.y), f2bf(v0.z), f2bf(v0.w) };
        ushort4 b = { f2bf(v1.x), f2bf(v1.y), f2bf(v1.z), f2bf(v1.w) };
        ushort4* xo = reinterpret_cast<ushort4*>(xb) + idx * 2;
        xo[0] = a; xo[1] = b;
        return;
    }
    if (bid < 4352) {
        // ---- transpose Wv -> wvT bf16 ----
        auto T = reinterpret_cast<unsigned short (*)[72]>(SM);   // [64][72]
        const int tb = bid - 4096;
        const int k0 = (tb >> 4) * 64, n0 = (tb & 15) * 64;
        const int r = tid >> 4, c4 = (tid & 15) * 4;
        #pragma unroll
        for (int i = 0; i < 4; i++) {
            int kr = r + i * 16;
            float4 v = *reinterpret_cast<const float4*>(&wv[(size_t)(k0 + kr) * 1024 + n0 + c4]);
            T[c4 + 0][kr] = f2bf(v.x);
            T[c4 + 1][kr] = f2bf(v.y);
            T[c4 + 2][kr] = f2bf(v.z);
            T[c4 + 3][kr] = f2bf(v.w);
        }
        __syncthreads();
        #pragma unroll
        for (int i = 0; i < 4; i++) {
            int n = r + i * 16;
            ushort4 v = *reinterpret_cast<const ushort4*>(&T[n][c4]);
            *reinterpret_cast<ushort4*>(&wvT[(size_t)(n0 + n) * 1024 + k0 + c4]) = v;
        }
        return;
    }

    // ---- g_gemm: 64x64 tile, BK=32, f32 inputs converted in staging ----
    unsigned short* As = SM;            // [64][32] ushort (swizzled)
    unsigned short* Bs = SM + 2048;
    const int gb = bid - 4352;          // 0..255
    const int bm = (gb >> 4) * 64, bn = (gb & 15) * 64;

    const int lane = tid & 63;
    const int wave = tid >> 6;
    const int wr = wave >> 1, wc = wave & 1;
    const int lr = lane & 15, kg = lane >> 4;

    const int srow = tid >> 2;                 // 0..63
    const int su   = tid & 3;                  // 16B unit
    const int sphys = (su ^ ((srow >> 1) & 3)) * 8;
    const int rphys = (kg ^ ((lr >> 1) & 3)) * 8;
    const int aoff = (wr * 32 + lr) * 32 + rphys;
    const int boff = (wc * 32 + lr) * 32 + rphys;

    f32x4 acc[2][2] = {};

    for (int k0 = 0; k0 < 1024; k0 += 32) {
        // stage A (wq rows bm..bm+63), B (wk rows bn..bn+63): 8 f32 -> 8 bf16 each
        {
            const float* pa = &wq[(size_t)(bm + srow) * 1024 + k0 + su * 8];
            float4 v0 = *reinterpret_cast<const float4*>(pa);
            float4 v1 = *reinterpret_cast<const float4*>(pa + 4);
            ushort4 u0 = { f2bf(v0.x), f2bf(v0.y), f2bf(v0.z), f2bf(v0.w) };
            ushort4 u1 = { f2bf(v1.x), f2bf(v1.y), f2bf(v1.z), f2bf(v1.w) };
            *reinterpret_cast<ushort4*>(&As[srow * 32 + sphys])     = u0;
            *reinterpret_cast<ushort4*>(&As[srow * 32 + sphys + 4]) = u1;
            const float* pb = &wk[(size_t)(bn + srow) * 1024 + k0 + su * 8];
            float4 w0 = *reinterpret_cast<const float4*>(pb);
            float4 w1 = *reinterpret_cast<const float4*>(pb + 4);
            ushort4 t0 = { f2bf(w0.x), f2bf(w0.y), f2bf(w0.z), f2bf(w0.w) };
            ushort4 t1 = { f2bf(w1.x), f2bf(w1.y), f2bf(w1.z), f2bf(w1.w) };
            *reinterpret_cast<ushort4*>(&Bs[srow * 32 + sphys])     = t0;
            *reinterpret_cast<ushort4*>(&Bs[srow * 32 + sphys + 4]) = t1;
        }
        __syncthreads();
        bf16x8 af[2], bf[2];
        #pragma unroll
        for (int mf = 0; mf < 2; mf++)
            af[mf] = *reinterpret_cast<const bf16x8*>(&As[aoff + mf * 512]);
        #pragma unroll
        for (int nf = 0; nf < 2; nf++)
            bf[nf] = *reinterpret_cast<const bf16x8*>(&Bs[boff + nf * 512]);
        #pragma unroll
        for (int mf = 0; mf < 2; mf++)
            #pragma unroll
            for (int nf = 0; nf < 2; nf++)
                acc[mf][nf] = __builtin_amdgcn_mfma_f32_16x16x32_bf16(af[mf], bf[nf], acc[mf][nf], 0, 0, 0);
        __syncthreads();
    }
    #pragma unroll
    for (int mf = 0; mf < 2; mf++)
        #pragma unroll
        for (int nf = 0; nf < 2; nf++)
            #pragma unroll
            for (int r = 0; r < 4; r++)
                Gt[(size_t)(bm + wr * 32 + mf * 16 + kg * 4 + r) * 1024
                   + bn + wc * 32 + nf * 16 + lr] = f2bf(acc[mf][nf][r]);
}

// ---------------- projections: z=0: y = x·G; z=1: vvT (transposed). grid 1024 ----------------
__global__ __launch_bounds__(256, 2) void proj_gemm(
    const unsigned short* __restrict__ xb, const unsigned short* __restrict__ Gt,
    const unsigned short* __restrict__ wvT,
    unsigned short* __restrict__ y, unsigned short* __restrict__ vvT)
{
    __shared__ unsigned short As[2 * 128 * 64], Bs[2 * 128 * 64];   // 64 KB
    const int bid = blockIdx.x;
    const int wg  = (bid & 7) * 128 + (bid >> 3);   // 1024 % 8 == 0, bijective
    const int z   = wg >> 9;
    const int rem = wg & 511;
    const int bm  = (rem >> 3) * 128;
    const int bn  = (rem & 7) * 128;
    const unsigned short* Bw = z ? wvT : Gt;

    f32x4 acc[4][4] = {};
    f32x4 os[4] = {};
    gemm4<16, false>(xb, Bw, 1024, 1024, bm, bn, As, Bs, acc, os);

    const int tid = threadIdx.x, lane = tid & 63, wave = tid >> 6;
    const int wr = wave >> 1, wc = wave & 1, lr = lane & 15, kg = lane >> 4;
    if (z == 0) {
        #pragma unroll
        for (int mf = 0; mf < 4; mf++)
            #pragma unroll
            for (int nf = 0; nf < 4; nf++)
                #pragma unroll
                for (int r = 0; r < 4; r++)
                    y[(size_t)(bm + wr * 64 + mf * 16 + kg * 4 + r) * 1024
                      + bn + wc * 64 + nf * 16 + lr] = f2bf(acc[mf][nf][r]);
    } else {
        const int batch = bm >> 11;                 // 128-tiles never span batches
        unsigned short* o = vvT + (size_t)batch * 1024 * 2048;
        #pragma unroll
        for (int mf = 0; mf < 4; mf++)
            #pragma unroll
            for (int nf = 0; nf < 4; nf++) {
                ushort4 v = { f2bf(acc[mf][nf][0]), f2bf(acc[mf][nf][1]),
                              f2bf(acc[mf][nf][2]), f2bf(acc[mf][nf][3]) };
                *reinterpret_cast<ushort4*>(
                    &o[(size_t)(bn + wc * 64 + nf * 16 + lr) * 2048
                       + (bm & 2047) + wr * 64 + mf * 16 + kg * 4]) = v;
            }
    }
}

// ---------------- scores: y[b]·xb[b]^T / 32, exp epilogue -> bf16 P. grid 1024 ----------------
__global__ __launch_bounds__(256, 2) void scores_gemm(
    const unsigned short* __restrict__ y, const unsigned short* __restrict__ xb,
    unsigned short* __restrict__ P)
{
    __shared__ unsigned short As[2 * 128 * 64], Bs[2 * 128 * 64];   // 64 KB
    const int bid = blockIdx.x;
    const int wg  = (bid & 7) * 128 + (bid >> 3);   // 1024 % 8 == 0
    const int z   = wg >> 8;
    const int rem = wg & 255;
    const int bm  = (rem >> 4) * 128;
    const int bn  = (rem & 15) * 128;
    const unsigned short* A = y  + (size_t)z * 2048 * 1024;
    const unsigned short* B = xb + (size_t)z * 2048 * 1024;
    unsigned short* out = P + (size_t)z * 2048 * 2048;

    f32x4 acc[4][4] = {};
    f32x4 os[4] = {};
    gemm4<16, false>(A, B, 1024, 1024, bm, bn, As, Bs, acc, os);

    const int tid = threadIdx.x, lane = tid & 63, wave = tid >> 6;
    const int wr = wave >> 1, wc = wave & 1, lr = lane & 15, kg = lane >> 4;
    #pragma unroll
    for (int mf = 0; mf < 4; mf++)
        #pragma unroll
        for (int nf = 0; nf < 4; nf++)
            #pragma unroll
            for (int r = 0; r < 4; r++)
                out[(size_t)(bm + wr * 64 + mf * 16 + kg * 4 + r) * 2048
                    + bn + wc * 64 + nf * 16 + lr]
                    = f2bf(__expf(acc[mf][nf][r] * 0.03125f));
}

// ---------------- PV: 128x128 tiles, K=2048, grid 512; ones-MFMA row-sums; out = acc/l ----------------
__global__ __launch_bounds__(256, 2) void pv_gemm(
    const unsigned short* __restrict__ P, const unsigned short* __restrict__ vvT,
    float* __restrict__ out)
{
    __shared__ unsigned short As[2 * 128 * 64], Bs[2 * 128 * 64];   // 64 KB
    const int bid = blockIdx.x;
    const int wg  = (bid & 7) * 64 + (bid >> 3);    // 512 % 8 == 0
    const int z   = wg >> 7;
    const int rem = wg & 127;
    const int bm  = (rem >> 3) * 128;
    const int bn  = (rem & 7) * 128;
    const unsigned short* A = P   + (size_t)z * 2048 * 2048;
    const unsigned short* B = vvT + (size_t)z * 1024 * 2048;
    float* o = out + (size_t)z * 2048 * 1024;

    f32x4 acc[4][4] = {};
    f32x4 os[4] = {};
    gemm4<32, true>(A, B, 2048, 2048, bm, bn, As, Bs, acc, os);

    const int tid = threadIdx.x, lane = tid & 63, wave = tid >> 6;
    const int wr = wave >> 1, wc = wave & 1, lr = lane & 15, kg = lane >> 4;

    // os[mf][r] = full row-sum for row (bm + wr*64 + mf*16 + kg*4 + r), lane-replicated.
    #pragma unroll
    for (int mf = 0; mf < 4; mf++)
        #pragma unroll
        for (int r = 0; r < 4; r++) {
            const float inv = 1.0f / os[mf][r];
            #pragma unroll
            for (int nf = 0; nf < 4; nf++)
                o[(size_t)(bm + wr * 64 + mf * 16 + kg * 4 + r) * 1024
                  + bn + wc * 64 + nf * 16 + lr] = acc[mf][nf][r] * inv;
        }
}

extern "C" void kernel_launch(void* const* d_in, const int* in_sizes, int n_in,
                              void* d_out, int out_size, void* d_ws, size_t ws_size,
                              hipStream_t stream) {
    const float* x  = (const float*)d_in[0];
    const float* wk = (const float*)d_in[1];
    const float* wq = (const float*)d_in[2];
    const float* wv = (const float*)d_in[3];
    float* out = (float*)d_out;

    char* ws = (char*)d_ws;
    const size_t MB = 1024 * 1024;
    unsigned short* xb  = (unsigned short*)(ws);             // 16MB  x bf16
    unsigned short* y   = (unsigned short*)(ws + 16 * MB);   // 16MB  x·G bf16
    unsigned short* Gt  = (unsigned short*)(ws + 32 * MB);   // 2MB   Gt[e,d]
    unsigned short* wvT = (unsigned short*)(ws + 34 * MB);   // 2MB
    unsigned short* vvT = (unsigned short*)(ws + 36 * MB);   // 16MB
    unsigned short* P   = (unsigned short*)(ws + 52 * MB);   // 32MB bf16 exp(s)

    stage1     <<<dim3(4608), 256, 0, stream>>>(x, xb, wv, wvT, wq, wk, Gt);
    proj_gemm  <<<dim3(1024), 256, 0, stream>>>(xb, Gt, wvT, y, vvT);
    scores_gemm<<<dim3(1024), 256, 0, stream>>>(y, xb, P);
    pv_gemm    <<<dim3(512),  256, 0, stream>>>(P, vvT, out);
}

// Round 11
// 155.742 us; speedup vs baseline: 1.2790x; 1.0869x over previous
//
#include <hip/hip_runtime.h>

// B=4, S=2048, D=1024. out = softmax((x@Wk)(x@Wq)^T / 32) @ (x@Wv), fp32 out.
// Algebra: Gt[e,d] = Wq[e,:]·Wk[d,:]; y = x·G (via B^T gemm vs Gt); scores = y·x^T.
// GEMM core identical to rounds 6/9/10: 128x128 tiles, 4 waves (2x2), BK=64,
// dbuf 64KB LDS (2 blocks/CU), 2-deep counted-vmcnt pipeline, 0-conflict
// XOR-swizzled LDS, XCD swizzle, setprio. Softmax fused: scores writes
// exp(s/32) bf16 P; pv row-sums via ones-MFMA (exact, shuffle-free).
// Stage 1: ONE launch; g_gemm blocks FIRST (overlap with converts) and
// register-prefetch pipelined (hide L2 latency under convert/MFMA).

typedef __attribute__((ext_vector_type(8))) short bf16x8;
typedef __attribute__((ext_vector_type(4))) float f32x4;

__device__ __forceinline__ unsigned short f2bf(float f) {
    unsigned int u = __float_as_uint(f);
    u += 0x7fff + ((u >> 16) & 1);   // RNE
    return (unsigned short)(u >> 16);
}

__device__ __forceinline__ void gld_lds16(const unsigned short* g, unsigned short* l) {
    __builtin_amdgcn_global_load_lds(
        (const __attribute__((address_space(1))) void*)g,
        (__attribute__((address_space(3))) void*)l, 16, 0, 0);
}

template<int N> __device__ __forceinline__ void vmcnt_wait() {
    if constexpr (N == 0) asm volatile("s_waitcnt vmcnt(0)" ::: "memory");
    else if constexpr (N == 8) asm volatile("s_waitcnt vmcnt(8)" ::: "memory");
}
__device__ __forceinline__ void bar() {
    asm volatile("" ::: "memory");
    __builtin_amdgcn_s_barrier();
    asm volatile("" ::: "memory");
}

// ---------------- 128x128x(64*KT) bf16 B^T GEMM, 4 waves (2x2) ----------------
// [core identical to rounds 6/9/10; RS = ones-MFMA row-sum into os]
template<int KT, bool RS>
__device__ __forceinline__ void gemm4(
    const unsigned short* __restrict__ A, const unsigned short* __restrict__ B,
    int lda, int ldb, int bm, int bn,
    unsigned short* As, unsigned short* Bs,
    f32x4 (&acc)[4][4], f32x4 (&os)[4])
{
    const int tid  = threadIdx.x;
    const int lane = tid & 63;
    const int wave = tid >> 6;            // 0..3
    const int wr = wave >> 1, wc = wave & 1;
    const int lr = lane & 15, kg = lane >> 4;

    const bf16x8 ONES = { (short)0x3F80, (short)0x3F80, (short)0x3F80, (short)0x3F80,
                          (short)0x3F80, (short)0x3F80, (short)0x3F80, (short)0x3F80 };

    const int srow = tid >> 2;                       // 0..63
    const int ssrc = ((tid & 3) ^ ((tid >> 3) & 3)) * 8;
    const unsigned short* pa0 = A + (size_t)(bm + srow) * lda + ssrc;
    const unsigned short* pa1 = A + (size_t)(bm + 64 + srow) * lda + ssrc;
    const unsigned short* pb0 = B + (size_t)(bn + srow) * ldb + ssrc;
    const unsigned short* pb1 = B + (size_t)(bn + 64 + srow) * ldb + ssrc;

    const int phys = (kg ^ ((lr >> 1) & 3)) * 8;
    const int aoff = (wr * 64 + lr) * 32 + phys;
    const int boff = (wc * 64 + lr) * 32 + phys;

    auto stage = [&](int buf, int kt) {
        unsigned short* da = As + buf * 8192 + wave * 512;
        unsigned short* db = Bs + buf * 8192 + wave * 512;
        #pragma unroll
        for (int kh = 0; kh < 2; kh++) {
            const int go = kt * 64 + kh * 32;
            gld_lds16(pa0 + go, da + kh * 4096);
            gld_lds16(pa1 + go, da + kh * 4096 + 2048);
            gld_lds16(pb0 + go, db + kh * 4096);
            gld_lds16(pb1 + go, db + kh * 4096 + 2048);
        }
    };

    stage(0, 0);
    stage(1, 1);
    vmcnt_wait<8>();
    bar();

    for (int kt = 0; kt < KT; ++kt) {
        const int c = kt & 1;
        const unsigned short* Ab = As + c * 8192 + aoff;
        const unsigned short* Bb = Bs + c * 8192 + boff;

        #pragma unroll
        for (int kh = 0; kh < 2; kh++) {
            bf16x8 af[4], bf[4];
            #pragma unroll
            for (int mf = 0; mf < 4; mf++)
                af[mf] = *reinterpret_cast<const bf16x8*>(Ab + kh * 4096 + mf * 512);
            #pragma unroll
            for (int nf = 0; nf < 4; nf++)
                bf[nf] = *reinterpret_cast<const bf16x8*>(Bb + kh * 4096 + nf * 512);
            __builtin_amdgcn_s_setprio(1);
            #pragma unroll
            for (int mf = 0; mf < 4; mf++)
                #pragma unroll
                for (int nf = 0; nf < 4; nf++)
                    acc[mf][nf] = __builtin_amdgcn_mfma_f32_16x16x32_bf16(af[mf], bf[nf], acc[mf][nf], 0, 0, 0);
            if constexpr (RS) {
                #pragma unroll
                for (int mf = 0; mf < 4; mf++)
                    os[mf] = __builtin_amdgcn_mfma_f32_16x16x32_bf16(af[mf], ONES, os[mf], 0, 0, 0);
            }
            __builtin_amdgcn_s_setprio(0);
        }

        if (kt == KT - 1) break;
        bar();                     // all waves done reading buf c
        if (kt + 2 < KT) {
            stage(c, kt + 2);      // overwrite buf c with tile kt+2
            vmcnt_wait<8>();       // tile kt+1 (issued a full tile ago) landed
        } else {
            vmcnt_wait<0>();
        }
        bar();                     // buf (kt+1)&1 globally ready
    }
}

// ================ stage 1 (merged): g_gemm | convert_x | transpose_wv ================
// blocks [0,256):      Gt[m,n] = sum_j Wq[m,j]*Wk[n,j]  (64x64 tiles, reg-prefetch pipelined)
// blocks [256,4352):   x f32 -> xb bf16
// blocks [4352,4608):  Wv [k][n] f32 -> wvT [n][k] bf16
__global__ __launch_bounds__(256) void stage1(
    const float* __restrict__ x,  unsigned short* __restrict__ xb,
    const float* __restrict__ wv, unsigned short* __restrict__ wvT,
    const float* __restrict__ wq, const float* __restrict__ wk,
    unsigned short* __restrict__ Gt)
{
    __shared__ unsigned short SM[4608];
    const int bid = blockIdx.x;
    const int tid = threadIdx.x;

    if (bid >= 256 && bid < 4352) {
        // ---- convert x -> bf16, 8 elems/thread ----
        const size_t idx = (size_t)(bid - 256) * 256 + tid;
        const float4* xi = reinterpret_cast<const float4*>(x) + idx * 2;
        float4 v0 = xi[0], v1 = xi[1];
        ushort4 a = { f2bf(v0.x), f2bf(v0.y), f2bf(v0.z), f2bf(v0.w) };
        ushort4 b = { f2bf(v1.x), f2bf(v1.y), f2bf(v1.z), f2bf(v1.w) };
        ushort4* xo = reinterpret_cast<ushort4*>(xb) + idx * 2;
        xo[0] = a; xo[1] = b;
        return;
    }
    if (bid >= 4352) {
        // ---- transpose Wv -> wvT bf16 ----
        auto T = reinterpret_cast<unsigned short (*)[72]>(SM);   // [64][72]
        const int tb = bid - 4352;
        const int k0 = (tb >> 4) * 64, n0 = (tb & 15) * 64;
        const int r = tid >> 4, c4 = (tid & 15) * 4;
        #pragma unroll
        for (int i = 0; i < 4; i++) {
            int kr = r + i * 16;
            float4 v = *reinterpret_cast<const float4*>(&wv[(size_t)(k0 + kr) * 1024 + n0 + c4]);
            T[c4 + 0][kr] = f2bf(v.x);
            T[c4 + 1][kr] = f2bf(v.y);
            T[c4 + 2][kr] = f2bf(v.z);
            T[c4 + 3][kr] = f2bf(v.w);
        }
        __syncthreads();
        #pragma unroll
        for (int i = 0; i < 4; i++) {
            int n = r + i * 16;
            ushort4 v = *reinterpret_cast<const ushort4*>(&T[n][c4]);
            *reinterpret_cast<ushort4*>(&wvT[(size_t)(n0 + n) * 1024 + k0 + c4]) = v;
        }
        return;
    }

    // ---- g_gemm: 64x64 tile, BK=32, reg-prefetch pipelined, f32->bf16 in staging ----
    unsigned short* As = SM;            // [64][32] ushort (swizzled)
    unsigned short* Bs = SM + 2048;
    const int gb = bid;                 // 0..255
    const int bm = (gb >> 4) * 64, bn = (gb & 15) * 64;

    const int lane = tid & 63;
    const int wave = tid >> 6;
    const int wr = wave >> 1, wc = wave & 1;
    const int lr = lane & 15, kg = lane >> 4;

    const int srow = tid >> 2;                 // 0..63
    const int su   = tid & 3;                  // 16B dest unit
    const int sphys = (su ^ ((srow >> 1) & 3)) * 8;
    const int rphys = (kg ^ ((lr >> 1) & 3)) * 8;
    const int aoff = (wr * 32 + lr) * 32 + rphys;
    const int boff = (wc * 32 + lr) * 32 + rphys;

    const float* pa = &wq[(size_t)(bm + srow) * 1024 + su * 8];
    const float* pb = &wk[(size_t)(bn + srow) * 1024 + su * 8];

    f32x4 acc[2][2] = {};

    // prologue: tile 0 in registers
    float4 a0 = *reinterpret_cast<const float4*>(pa);
    float4 a1 = *reinterpret_cast<const float4*>(pa + 4);
    float4 b0 = *reinterpret_cast<const float4*>(pb);
    float4 b1 = *reinterpret_cast<const float4*>(pb + 4);

    for (int k0 = 0; k0 < 1024; k0 += 32) {
        // convert + write current tile
        ushort4 u0 = { f2bf(a0.x), f2bf(a0.y), f2bf(a0.z), f2bf(a0.w) };
        ushort4 u1 = { f2bf(a1.x), f2bf(a1.y), f2bf(a1.z), f2bf(a1.w) };
        *reinterpret_cast<ushort4*>(&As[srow * 32 + sphys])     = u0;
        *reinterpret_cast<ushort4*>(&As[srow * 32 + sphys + 4]) = u1;
        ushort4 t0 = { f2bf(b0.x), f2bf(b0.y), f2bf(b0.z), f2bf(b0.w) };
        ushort4 t1 = { f2bf(b1.x), f2bf(b1.y), f2bf(b1.z), f2bf(b1.w) };
        *reinterpret_cast<ushort4*>(&Bs[srow * 32 + sphys])     = t0;
        *reinterpret_cast<ushort4*>(&Bs[srow * 32 + sphys + 4]) = t1;

        // prefetch next tile into registers (hides L2 latency under MFMA phase)
        if (k0 + 32 < 1024) {
            const float* npa = pa + k0 + 32;
            const float* npb = pb + k0 + 32;
            a0 = *reinterpret_cast<const float4*>(npa);
            a1 = *reinterpret_cast<const float4*>(npa + 4);
            b0 = *reinterpret_cast<const float4*>(npb);
            b1 = *reinterpret_cast<const float4*>(npb + 4);
        }
        __syncthreads();

        bf16x8 af[2], bf[2];
        #pragma unroll
        for (int mf = 0; mf < 2; mf++)
            af[mf] = *reinterpret_cast<const bf16x8*>(&As[aoff + mf * 512]);
        #pragma unroll
        for (int nf = 0; nf < 2; nf++)
            bf[nf] = *reinterpret_cast<const bf16x8*>(&Bs[boff + nf * 512]);
        #pragma unroll
        for (int mf = 0; mf < 2; mf++)
            #pragma unroll
            for (int nf = 0; nf < 2; nf++)
                acc[mf][nf] = __builtin_amdgcn_mfma_f32_16x16x32_bf16(af[mf], bf[nf], acc[mf][nf], 0, 0, 0);
        __syncthreads();
    }
    #pragma unroll
    for (int mf = 0; mf < 2; mf++)
        #pragma unroll
        for (int nf = 0; nf < 2; nf++)
            #pragma unroll
            for (int r = 0; r < 4; r++)
                Gt[(size_t)(bm + wr * 32 + mf * 16 + kg * 4 + r) * 1024
                   + bn + wc * 32 + nf * 16 + lr] = f2bf(acc[mf][nf][r]);
}

// ---------------- projections: z=0: y = x·G; z=1: vvT (transposed). grid 1024 ----------------
__global__ __launch_bounds__(256, 2) void proj_gemm(
    const unsigned short* __restrict__ xb, const unsigned short* __restrict__ Gt,
    const unsigned short* __restrict__ wvT,
    unsigned short* __restrict__ y, unsigned short* __restrict__ vvT)
{
    __shared__ unsigned short As[2 * 128 * 64], Bs[2 * 128 * 64];   // 64 KB
    const int bid = blockIdx.x;
    const int wg  = (bid & 7) * 128 + (bid >> 3);   // 1024 % 8 == 0, bijective
    const int z   = wg >> 9;
    const int rem = wg & 511;
    const int bm  = (rem >> 3) * 128;
    const int bn  = (rem & 7) * 128;
    const unsigned short* Bw = z ? wvT : Gt;

    f32x4 acc[4][4] = {};
    f32x4 os[4] = {};
    gemm4<16, false>(xb, Bw, 1024, 1024, bm, bn, As, Bs, acc, os);

    const int tid = threadIdx.x, lane = tid & 63, wave = tid >> 6;
    const int wr = wave >> 1, wc = wave & 1, lr = lane & 15, kg = lane >> 4;
    if (z == 0) {
        #pragma unroll
        for (int mf = 0; mf < 4; mf++)
            #pragma unroll
            for (int nf = 0; nf < 4; nf++)
                #pragma unroll
                for (int r = 0; r < 4; r++)
                    y[(size_t)(bm + wr * 64 + mf * 16 + kg * 4 + r) * 1024
                      + bn + wc * 64 + nf * 16 + lr] = f2bf(acc[mf][nf][r]);
    } else {
        const int batch = bm >> 11;                 // 128-tiles never span batches
        unsigned short* o = vvT + (size_t)batch * 1024 * 2048;
        #pragma unroll
        for (int mf = 0; mf < 4; mf++)
            #pragma unroll
            for (int nf = 0; nf < 4; nf++) {
                ushort4 v = { f2bf(acc[mf][nf][0]), f2bf(acc[mf][nf][1]),
                              f2bf(acc[mf][nf][2]), f2bf(acc[mf][nf][3]) };
                *reinterpret_cast<ushort4*>(
                    &o[(size_t)(bn + wc * 64 + nf * 16 + lr) * 2048
                       + (bm & 2047) + wr * 64 + mf * 16 + kg * 4]) = v;
            }
    }
}

// ---------------- scores: y[b]·xb[b]^T / 32, exp epilogue -> bf16 P. grid 1024 ----------------
__global__ __launch_bounds__(256, 2) void scores_gemm(
    const unsigned short* __restrict__ y, const unsigned short* __restrict__ xb,
    unsigned short* __restrict__ P)
{
    __shared__ unsigned short As[2 * 128 * 64], Bs[2 * 128 * 64];   // 64 KB
    const int bid = blockIdx.x;
    const int wg  = (bid & 7) * 128 + (bid >> 3);   // 1024 % 8 == 0
    const int z   = wg >> 8;
    const int rem = wg & 255;
    const int bm  = (rem >> 4) * 128;
    const int bn  = (rem & 15) * 128;
    const unsigned short* A = y  + (size_t)z * 2048 * 1024;
    const unsigned short* B = xb + (size_t)z * 2048 * 1024;
    unsigned short* out = P + (size_t)z * 2048 * 2048;

    f32x4 acc[4][4] = {};
    f32x4 os[4] = {};
    gemm4<16, false>(A, B, 1024, 1024, bm, bn, As, Bs, acc, os);

    const int tid = threadIdx.x, lane = tid & 63, wave = tid >> 6;
    const int wr = wave >> 1, wc = wave & 1, lr = lane & 15, kg = lane >> 4;
    #pragma unroll
    for (int mf = 0; mf < 4; mf++)
        #pragma unroll
        for (int nf = 0; nf < 4; nf++)
            #pragma unroll
            for (int r = 0; r < 4; r++)
                out[(size_t)(bm + wr * 64 + mf * 16 + kg * 4 + r) * 2048
                    + bn + wc * 64 + nf * 16 + lr]
                    = f2bf(__expf(acc[mf][nf][r] * 0.03125f));
}

// ---------------- PV: 128x128 tiles, K=2048, grid 512; ones-MFMA row-sums; out = acc/l ----------------
__global__ __launch_bounds__(256, 2) void pv_gemm(
    const unsigned short* __restrict__ P, const unsigned short* __restrict__ vvT,
    float* __restrict__ out)
{
    __shared__ unsigned short As[2 * 128 * 64], Bs[2 * 128 * 64];   // 64 KB
    const int bid = blockIdx.x;
    const int wg  = (bid & 7) * 64 + (bid >> 3);    // 512 % 8 == 0
    const int z   = wg >> 7;
    const int rem = wg & 127;
    const int bm  = (rem >> 3) * 128;
    const int bn  = (rem & 7) * 128;
    const unsigned short* A = P   + (size_t)z * 2048 * 2048;
    const unsigned short* B = vvT + (size_t)z * 1024 * 2048;
    float* o = out + (size_t)z * 2048 * 1024;

    f32x4 acc[4][4] = {};
    f32x4 os[4] = {};
    gemm4<32, true>(A, B, 2048, 2048, bm, bn, As, Bs, acc, os);

    const int tid = threadIdx.x, lane = tid & 63, wave = tid >> 6;
    const int wr = wave >> 1, wc = wave & 1, lr = lane & 15, kg = lane >> 4;

    // os[mf][r] = full row-sum for row (bm + wr*64 + mf*16 + kg*4 + r), lane-replicated.
    #pragma unroll
    for (int mf = 0; mf < 4; mf++)
        #pragma unroll
        for (int r = 0; r < 4; r++) {
            const float inv = 1.0f / os[mf][r];
            #pragma unroll
            for (int nf = 0; nf < 4; nf++)
                o[(size_t)(bm + wr * 64 + mf * 16 + kg * 4 + r) * 1024
                  + bn + wc * 64 + nf * 16 + lr] = acc[mf][nf][r] * inv;
        }
}

extern "C" void kernel_launch(void* const* d_in, const int* in_sizes, int n_in,
                              void* d_out, int out_size, void* d_ws, size_t ws_size,
                              hipStream_t stream) {
    const float* x  = (const float*)d_in[0];
    const float* wk = (const float*)d_in[1];
    const float* wq = (const float*)d_in[2];
    const float* wv = (const float*)d_in[3];
    float* out = (float*)d_out;

    char* ws = (char*)d_ws;
    const size_t MB = 1024 * 1024;
    unsigned short* xb  = (unsigned short*)(ws);             // 16MB  x bf16
    unsigned short* y   = (unsigned short*)(ws + 16 * MB);   // 16MB  x·G bf16
    unsigned short* Gt  = (unsigned short*)(ws + 32 * MB);   // 2MB   Gt[e,d]
    unsigned short* wvT = (unsigned short*)(ws + 34 * MB);   // 2MB
    unsigned short* vvT = (unsigned short*)(ws + 36 * MB);   // 16MB
    unsigned short* P   = (unsigned short*)(ws + 52 * MB);   // 32MB bf16 exp(s)

    stage1     <<<dim3(4608), 256, 0, stream>>>(x, xb, wv, wvT, wq, wk, Gt);
    proj_gemm  <<<dim3(1024), 256, 0, stream>>>(xb, Gt, wvT, y, vvT);
    scores_gemm<<<dim3(1024), 256, 0, stream>>>(y, xb, P);
    pv_gemm    <<<dim3(512),  256, 0, stream>>>(P, vvT, out);
}